// Round 1
// baseline (833.536 us; speedup 1.0000x reference)
//
#include <hip/hip_runtime.h>
#include <cstdint>
#include <cstddef>

typedef short short8 __attribute__((ext_vector_type(8)));
typedef float f32x4 __attribute__((ext_vector_type(4)));

#define DIN  4096
#define DOUT 4096
#define RANK 64
#define NEXP 16
#define NTOK 8192
#define KCAT 5120   // DIN + NEXP*RANK

// ---------- helpers ----------
__device__ __forceinline__ unsigned short f2bf(float f) {
    unsigned int u = __builtin_bit_cast(unsigned int, f);
    u = (u + 0x7FFFu + ((u >> 16) & 1u)) >> 16;   // RNE
    return (unsigned short)u;
}
__device__ __forceinline__ float bf2f(unsigned short h) {
    unsigned int u = ((unsigned int)h) << 16;
    return __builtin_bit_cast(float, u);
}
__device__ __forceinline__ void async_cp16(const void* g, void* lds) {
    __builtin_amdgcn_global_load_lds(
        (const __attribute__((address_space(1))) void*)g,
        (__attribute__((address_space(3))) void*)lds, 16, 0, 0);
}

// ---------- kernel 1: pack weights ----------
// Wcat[o][0:4096]    = bf16(base_w[o][:])
// Wcat[o][4096+e*64+r] = bf16(B[e][o][r])
// W1[0:64][:]  = bf16(A);  W1[64:80][:] = bf16(rw) hi;  W1[80:96][:] = bf16(rw - hi)
__global__ void __launch_bounds__(256) prep_w_kernel(
        const float* __restrict__ bw, const float* __restrict__ Bm,
        const float* __restrict__ Am, const float* __restrict__ rw,
        unsigned short* __restrict__ Wcat, unsigned short* __restrict__ W1) {
    const unsigned NG1 = (unsigned)DOUT * KCAT / 8u;       // 2,621,440
    const unsigned NGT = NG1 + 96u * DIN / 8u;             // + 49,152
    for (unsigned g = blockIdx.x * blockDim.x + threadIdx.x; g < NGT;
         g += gridDim.x * blockDim.x) {
        const float* src;
        unsigned short* dst;
        int mode = 0;  // 0 = hi, 1 = lo residual
        if (g < NG1) {
            unsigned o  = g / 640u;
            unsigned c8 = (g - o * 640u) * 8u;
            dst = Wcat + (size_t)o * KCAT + c8;
            if (c8 < DIN) {
                src = bw + (size_t)o * DIN + c8;
            } else {
                unsigned cc = c8 - DIN;
                unsigned e = cc >> 6, r = cc & 63u;
                src = Bm + ((size_t)e * DOUT + o) * RANK + r;
            }
        } else {
            unsigned g2 = g - NG1;
            unsigned row = g2 / 512u;
            unsigned c8  = (g2 - row * 512u) * 8u;
            dst = W1 + (size_t)row * DIN + c8;
            if (row < 64u)       src = Am + (size_t)row * DIN + c8;
            else if (row < 80u)  src = rw + (size_t)(row - 64u) * DIN + c8;
            else               { src = rw + (size_t)(row - 80u) * DIN + c8; mode = 1; }
        }
        float4 v0 = *(const float4*)(src);
        float4 v1 = *(const float4*)(src + 4);
        float vv[8] = {v0.x, v0.y, v0.z, v0.w, v1.x, v1.y, v1.z, v1.w};
        unsigned short o16[8];
        #pragma unroll
        for (int i = 0; i < 8; ++i) {
            unsigned short h = f2bf(vv[i]);
            if (mode) h = f2bf(vv[i] - bf2f(h));
            o16[i] = h;
        }
        uint4 pk;
        pk.x = (unsigned)o16[0] | ((unsigned)o16[1] << 16);
        pk.y = (unsigned)o16[2] | ((unsigned)o16[3] << 16);
        pk.z = (unsigned)o16[4] | ((unsigned)o16[5] << 16);
        pk.w = (unsigned)o16[6] | ((unsigned)o16[7] << 16);
        *(uint4*)dst = pk;
    }
}

// ---------- kernel 2: convert x, router lo-correction, zero Z ----------
// block = 256 threads, 8 tokens.  Corr[t][e] = sum_k xl[t][k]*rw[e][k] (fp32)
__global__ void __launch_bounds__(256) prep_x_kernel(
        const float* __restrict__ x, const float* __restrict__ rw,
        unsigned short* __restrict__ Xcat, float* __restrict__ Corr,
        float* __restrict__ Z) {
    __shared__ __align__(16) float xsl[8][532];     // padded rows: 2-way conflicts only
    __shared__ __align__(16) float red[8][16][16];  // [t][e][c]
    const int tid = threadIdx.x;

    // zero Z (8192*96 floats = 196608 float4)
    {
        unsigned gtid = blockIdx.x * 256u + tid;
        if (gtid < (unsigned)(NTOK * 96 / 4)) {
            f32x4 z = {0.f, 0.f, 0.f, 0.f};
            ((f32x4*)Z)[gtid] = z;
        }
    }
    const int t0 = blockIdx.x * 8;
    const int tt = tid >> 5, l32 = tid & 31;            // phase A mapping
    const int eg = tid >> 6, ts = (tid >> 4) & 3, cc = tid & 15;  // phase B mapping
    float part[2][4] = {};

    for (int w = 0; w < 8; ++w) {
        // phase A: load x window [8 tok x 512], write bf16 hi, stash lo in LDS
        #pragma unroll
        for (int sub = 0; sub < 4; ++sub) {
            const int col = w * 512 + sub * 128 + l32 * 4;
            const float4 xv = *(const float4*)&x[(size_t)(t0 + tt) * DIN + col];
            unsigned short b0 = f2bf(xv.x), b1 = f2bf(xv.y),
                           b2 = f2bf(xv.z), b3 = f2bf(xv.w);
            uint2 pk = { (unsigned)b0 | ((unsigned)b1 << 16),
                         (unsigned)b2 | ((unsigned)b3 << 16) };
            *(uint2*)&Xcat[(size_t)(t0 + tt) * KCAT + col] = pk;
            float4 xl = { xv.x - bf2f(b0), xv.y - bf2f(b1),
                          xv.z - bf2f(b2), xv.w - bf2f(b3) };
            *(float4*)&xsl[tt][sub * 128 + l32 * 4] = xl;
        }
        __syncthreads();
        // phase B: Corr partials.  thread = (eg: 4 experts, ts: 2 tokens, cc)
        #pragma unroll
        for (int j = 0; j < 8; ++j) {
            const int colb = w * 512 + (j * 16 + cc) * 4;
            const float4 r0 = *(const float4*)&rw[(size_t)(eg * 4 + 0) * DIN + colb];
            const float4 r1 = *(const float4*)&rw[(size_t)(eg * 4 + 1) * DIN + colb];
            const float4 r2 = *(const float4*)&rw[(size_t)(eg * 4 + 2) * DIN + colb];
            const float4 r3 = *(const float4*)&rw[(size_t)(eg * 4 + 3) * DIN + colb];
            #pragma unroll
            for (int t2 = 0; t2 < 2; ++t2) {
                const int t = ts * 2 + t2;
                const float4 xv = *(const float4*)&xsl[t][(j * 16 + cc) * 4];
                part[t2][0] += xv.x * r0.x + xv.y * r0.y + xv.z * r0.z + xv.w * r0.w;
                part[t2][1] += xv.x * r1.x + xv.y * r1.y + xv.z * r1.z + xv.w * r1.w;
                part[t2][2] += xv.x * r2.x + xv.y * r2.y + xv.z * r2.z + xv.w * r2.w;
                part[t2][3] += xv.x * r3.x + xv.y * r3.y + xv.z * r3.z + xv.w * r3.w;
            }
        }
        __syncthreads();
    }
    #pragma unroll
    for (int t2 = 0; t2 < 2; ++t2)
        #pragma unroll
        for (int e = 0; e < 4; ++e)
            red[ts * 2 + t2][eg * 4 + e][cc] = part[t2][e];
    __syncthreads();
    if (tid < 128) {
        const int t = tid >> 4, e = tid & 15;
        float s = 0.f;
        #pragma unroll
        for (int c = 0; c < 16; ++c) s += red[t][e][c];
        Corr[(size_t)(t0 + t) * NEXP + e] = s;
    }
}

// ---------- kernel 3: Z = Xhi @ W1^T  (M=8192, N=96, K=4096), split-K=8 ----------
__global__ void __launch_bounds__(256) gemm_prep_kernel(
        const unsigned short* __restrict__ Xcat,
        const unsigned short* __restrict__ W1, float* __restrict__ Z) {
    __shared__ __align__(16) unsigned short Xs[128 * 64];
    __shared__ __align__(16) unsigned short Ws[96 * 64];
    const int tid = threadIdx.x;
    const int wave = tid >> 6, lane = tid & 63;
    const int quad = lane >> 4, l16 = lane & 15;
    const int bm0 = blockIdx.x * 128;
    const int ks0 = blockIdx.y * 512;
    const int srow = tid >> 3;
    const int scol = (tid & 7) * 8;
    const int wm = wave * 32;
    f32x4 acc[2][6] = {};
    for (int kt = 0; kt < 8; ++kt) {
        const int k0 = ks0 + kt * 64;
        #pragma unroll
        for (int i = 0; i < 4; ++i)
            async_cp16(Xcat + (size_t)(bm0 + i * 32 + srow) * KCAT + k0 + scol,
                       (char*)Xs + i * 4096 + wave * 1024);
        #pragma unroll
        for (int i = 0; i < 3; ++i)
            async_cp16(W1 + (size_t)(i * 32 + srow) * DIN + k0 + scol,
                       (char*)Ws + i * 4096 + wave * 1024);
        __syncthreads();
        #pragma unroll
        for (int kk = 0; kk < 2; ++kk) {
            short8 am[2], bn[6];
            #pragma unroll
            for (int i = 0; i < 2; ++i)
                am[i] = *(const short8*)&Xs[(wm + i * 16 + l16) * 64 + kk * 32 + quad * 8];
            #pragma unroll
            for (int j = 0; j < 6; ++j)
                bn[j] = *(const short8*)&Ws[(j * 16 + l16) * 64 + kk * 32 + quad * 8];
            #pragma unroll
            for (int i = 0; i < 2; ++i)
                #pragma unroll
                for (int j = 0; j < 6; ++j)
                    acc[i][j] = __builtin_amdgcn_mfma_f32_16x16x32_bf16(
                        am[i], bn[j], acc[i][j], 0, 0, 0);
        }
        __syncthreads();
    }
    #pragma unroll
    for (int i = 0; i < 2; ++i) {
        const int row0 = bm0 + wm + i * 16 + quad * 4;
        #pragma unroll
        for (int j = 0; j < 6; ++j) {
            const int col = j * 16 + l16;
            #pragma unroll
            for (int r = 0; r < 4; ++r)
                atomicAdd(&Z[(size_t)(row0 + r) * 96 + col], acc[i][j][r]);
        }
    }
}

// ---------- kernel 4: softmax + top2 + build H16 ----------
__global__ void __launch_bounds__(256) finalize_kernel(
        const float* __restrict__ Z, const float* __restrict__ Corr,
        unsigned short* __restrict__ Xcat) {
    __shared__ __align__(16) unsigned short hb[4][1024];
    const int tid = threadIdx.x, wv = tid >> 6, lane = tid & 63;
    const int t = blockIdx.x * 4 + wv;
    const float h = Z[(size_t)t * 96 + lane];
    float l[16];
    #pragma unroll
    for (int e = 0; e < 16; ++e)
        l[e] = Z[(size_t)t * 96 + 64 + e] + Z[(size_t)t * 96 + 80 + e]
             + Corr[(size_t)t * NEXP + e];
    int i1 = 0; float b1v = l[0];
    #pragma unroll
    for (int e = 1; e < 16; ++e) if (l[e] > b1v) { b1v = l[e]; i1 = e; }
    int i2 = -1; float b2v = -1e30f;
    #pragma unroll
    for (int e = 0; e < 16; ++e) if (e != i1 && l[e] > b2v) { b2v = l[e]; i2 = e; }
    float S = 0.f;
    #pragma unroll
    for (int e = 0; e < 16; ++e) S += expf(l[e] - b1v);
    const float t1 = 1.0f / S;                 // p[i1]
    const float t2 = expf(b2v - b1v) / S;      // p[i2]
    const float d = t1 + t2 + 1e-6f;
    const float c1 = 0.5f * t1 / d;            // fold SCALING=0.5
    const float c2 = 0.5f * t2 / d;
    #pragma unroll
    for (int e = 0; e < 16; ++e) {
        const float v = (e == i1) ? c1 * h : (e == i2) ? c2 * h : 0.0f;
        hb[wv][e * 64 + lane] = f2bf(v);
    }
    __syncthreads();
    uint4* dst = (uint4*)(Xcat + (size_t)t * KCAT + DIN);
    const uint4* src = (const uint4*)hb[wv];
    dst[lane * 2] = src[lane * 2];
    dst[lane * 2 + 1] = src[lane * 2 + 1];
}

// ---------- kernel 5: out = Xcat @ Wcat^T + bias  (M=8192,N=4096,K=5120) ----------
__global__ void __launch_bounds__(256) gemm_main_kernel(
        const unsigned short* __restrict__ Xcat,
        const unsigned short* __restrict__ Wcat,
        const float* __restrict__ bias, float* __restrict__ out) {
    __shared__ __align__(16) unsigned short Xs[128 * 64];
    __shared__ __align__(16) unsigned short Ws[128 * 64];
    const int tid = threadIdx.x;
    const int wave = tid >> 6, lane = tid & 63;
    const int quad = lane >> 4, l16 = lane & 15;
    const int bn0 = blockIdx.x * 128;
    const int bm0 = blockIdx.y * 128;
    const int srow = tid >> 3;
    const int scol = (tid & 7) * 8;
    const unsigned short* gx = Xcat + (size_t)(bm0 + srow) * KCAT + scol;
    const unsigned short* gw = Wcat + (size_t)(bn0 + srow) * KCAT + scol;
    const int wm0 = (wave & 1) * 64;
    const int wn0 = (wave >> 1) * 64;
    f32x4 acc[4][4] = {};
    for (int kt = 0; kt < KCAT / 64; ++kt) {
        const int k0 = kt * 64;
        #pragma unroll
        for (int i = 0; i < 4; ++i) {
            async_cp16(gx + (size_t)(i * 32) * KCAT + k0, (char*)Xs + i * 4096 + wave * 1024);
            async_cp16(gw + (size_t)(i * 32) * KCAT + k0, (char*)Ws + i * 4096 + wave * 1024);
        }
        __syncthreads();
        #pragma unroll
        for (int kk = 0; kk < 2; ++kk) {
            short8 am[4], bn[4];
            #pragma unroll
            for (int i = 0; i < 4; ++i)
                am[i] = *(const short8*)&Xs[(wm0 + i * 16 + l16) * 64 + kk * 32 + quad * 8];
            #pragma unroll
            for (int j = 0; j < 4; ++j)
                bn[j] = *(const short8*)&Ws[(wn0 + j * 16 + l16) * 64 + kk * 32 + quad * 8];
            #pragma unroll
            for (int i = 0; i < 4; ++i)
                #pragma unroll
                for (int j = 0; j < 4; ++j)
                    acc[i][j] = __builtin_amdgcn_mfma_f32_16x16x32_bf16(
                        am[i], bn[j], acc[i][j], 0, 0, 0);
        }
        __syncthreads();
    }
    #pragma unroll
    for (int j = 0; j < 4; ++j) {
        const int col = bn0 + wn0 + j * 16 + l16;
        const float bj = bias[col];
        #pragma unroll
        for (int i = 0; i < 4; ++i) {
            const int row0 = bm0 + wm0 + i * 16 + quad * 4;
            #pragma unroll
            for (int r = 0; r < 4; ++r)
                out[(size_t)(row0 + r) * DOUT + col] = acc[i][j][r] + bj;
        }
    }
}

// ---------- host ----------
extern "C" void kernel_launch(void* const* d_in, const int* in_sizes, int n_in,
                              void* d_out, int out_size, void* d_ws, size_t ws_size,
                              hipStream_t stream) {
    const float* x  = (const float*)d_in[0];
    const float* bw = (const float*)d_in[1];
    const float* bb = (const float*)d_in[2];
    const float* Am = (const float*)d_in[3];
    const float* Bm = (const float*)d_in[4];
    const float* rw = (const float*)d_in[5];
    float* out = (float*)d_out;
    char* ws = (char*)d_ws;
    // ws layout (bytes):
    unsigned short* Xcat = (unsigned short*)(ws);                 // 8192*5120*2 = 83,886,080
    unsigned short* Wcat = (unsigned short*)(ws + 83886080);      // 4096*5120*2 = 41,943,040
    unsigned short* W1   = (unsigned short*)(ws + 125829120);     // 96*4096*2   =    786,432
    float* Z    = (float*)(ws + 126615552);                       // 8192*96*4   =  3,145,728
    float* Corr = (float*)(ws + 129761280);                       // 8192*16*4   =    524,288

    hipLaunchKernelGGL(prep_w_kernel,   dim3(4096),   dim3(256), 0, stream, bw, Bm, Am, rw, Wcat, W1);
    hipLaunchKernelGGL(prep_x_kernel,   dim3(1024),   dim3(256), 0, stream, x, rw, Xcat, Corr, Z);
    hipLaunchKernelGGL(gemm_prep_kernel,dim3(64, 8),  dim3(256), 0, stream, Xcat, W1, Z);
    hipLaunchKernelGGL(finalize_kernel, dim3(2048),   dim3(256), 0, stream, Z, Corr, Xcat);
    hipLaunchKernelGGL(gemm_main_kernel,dim3(32, 64), dim3(256), 0, stream, Xcat, Wcat, bb, out);
}

// Round 2
// 742.911 us; speedup vs baseline: 1.1220x; 1.1220x over previous
//
#include <hip/hip_runtime.h>
#include <cstdint>
#include <cstddef>

typedef short short8 __attribute__((ext_vector_type(8)));
typedef float f32x4 __attribute__((ext_vector_type(4)));

#define DIN  4096
#define DOUT 4096
#define RANK 64
#define NEXP 16
#define NTOK 8192
#define KCAT 5120   // DIN + NEXP*RANK

// ---------- helpers ----------
__device__ __forceinline__ unsigned short f2bf(float f) {
    unsigned int u = __builtin_bit_cast(unsigned int, f);
    u = (u + 0x7FFFu + ((u >> 16) & 1u)) >> 16;   // RNE
    return (unsigned short)u;
}
__device__ __forceinline__ float bf2f(unsigned short h) {
    unsigned int u = ((unsigned int)h) << 16;
    return __builtin_bit_cast(float, u);
}
__device__ __forceinline__ void async_cp16(const void* g, void* lds) {
    __builtin_amdgcn_global_load_lds(
        (const __attribute__((address_space(1))) void*)g,
        (__attribute__((address_space(3))) void*)lds, 16, 0, 0);
}

// ---------- kernel 1: pack weights ----------
__global__ void __launch_bounds__(256) prep_w_kernel(
        const float* __restrict__ bw, const float* __restrict__ Bm,
        const float* __restrict__ Am, const float* __restrict__ rw,
        unsigned short* __restrict__ Wcat, unsigned short* __restrict__ W1) {
    const unsigned NG1 = (unsigned)DOUT * KCAT / 8u;       // 2,621,440
    const unsigned NGT = NG1 + 96u * DIN / 8u;             // + 49,152
    for (unsigned g = blockIdx.x * blockDim.x + threadIdx.x; g < NGT;
         g += gridDim.x * blockDim.x) {
        const float* src;
        unsigned short* dst;
        int mode = 0;  // 0 = hi, 1 = lo residual
        if (g < NG1) {
            unsigned o  = g / 640u;
            unsigned c8 = (g - o * 640u) * 8u;
            dst = Wcat + (size_t)o * KCAT + c8;
            if (c8 < DIN) {
                src = bw + (size_t)o * DIN + c8;
            } else {
                unsigned cc = c8 - DIN;
                unsigned e = cc >> 6, r = cc & 63u;
                src = Bm + ((size_t)e * DOUT + o) * RANK + r;
            }
        } else {
            unsigned g2 = g - NG1;
            unsigned row = g2 / 512u;
            unsigned c8  = (g2 - row * 512u) * 8u;
            dst = W1 + (size_t)row * DIN + c8;
            if (row < 64u)       src = Am + (size_t)row * DIN + c8;
            else if (row < 80u)  src = rw + (size_t)(row - 64u) * DIN + c8;
            else               { src = rw + (size_t)(row - 80u) * DIN + c8; mode = 1; }
        }
        float4 v0 = *(const float4*)(src);
        float4 v1 = *(const float4*)(src + 4);
        float vv[8] = {v0.x, v0.y, v0.z, v0.w, v1.x, v1.y, v1.z, v1.w};
        unsigned short o16[8];
        #pragma unroll
        for (int i = 0; i < 8; ++i) {
            unsigned short h = f2bf(vv[i]);
            if (mode) h = f2bf(vv[i] - bf2f(h));
            o16[i] = h;
        }
        uint4 pk;
        pk.x = (unsigned)o16[0] | ((unsigned)o16[1] << 16);
        pk.y = (unsigned)o16[2] | ((unsigned)o16[3] << 16);
        pk.z = (unsigned)o16[4] | ((unsigned)o16[5] << 16);
        pk.w = (unsigned)o16[6] | ((unsigned)o16[7] << 16);
        *(uint4*)dst = pk;
    }
}

// ---------- kernel 2: convert x, router lo-correction, zero Z ----------
__global__ void __launch_bounds__(256) prep_x_kernel(
        const float* __restrict__ x, const float* __restrict__ rw,
        unsigned short* __restrict__ Xcat, float* __restrict__ Corr,
        float* __restrict__ Z) {
    __shared__ __align__(16) float xsl[8][532];     // padded rows
    __shared__ __align__(16) float red[8][16][16];  // [t][e][c]
    const int tid = threadIdx.x;

    // zero Z (8192*96 floats = 196608 float4)
    {
        unsigned gtid = blockIdx.x * 256u + tid;
        if (gtid < (unsigned)(NTOK * 96 / 4)) {
            f32x4 z = {0.f, 0.f, 0.f, 0.f};
            ((f32x4*)Z)[gtid] = z;
        }
    }
    const int t0 = blockIdx.x * 8;
    const int tt = tid >> 5, l32 = tid & 31;            // phase A mapping
    const int eg = tid >> 6, ts = (tid >> 4) & 3, cc = tid & 15;  // phase B mapping
    float part[2][4] = {};

    for (int w = 0; w < 8; ++w) {
        #pragma unroll
        for (int sub = 0; sub < 4; ++sub) {
            const int col = w * 512 + sub * 128 + l32 * 4;
            const float4 xv = *(const float4*)&x[(size_t)(t0 + tt) * DIN + col];
            unsigned short b0 = f2bf(xv.x), b1 = f2bf(xv.y),
                           b2 = f2bf(xv.z), b3 = f2bf(xv.w);
            uint2 pk = { (unsigned)b0 | ((unsigned)b1 << 16),
                         (unsigned)b2 | ((unsigned)b3 << 16) };
            *(uint2*)&Xcat[(size_t)(t0 + tt) * KCAT + col] = pk;
            float4 xl = { xv.x - bf2f(b0), xv.y - bf2f(b1),
                          xv.z - bf2f(b2), xv.w - bf2f(b3) };
            *(float4*)&xsl[tt][sub * 128 + l32 * 4] = xl;
        }
        __syncthreads();
        #pragma unroll
        for (int j = 0; j < 8; ++j) {
            const int colb = w * 512 + (j * 16 + cc) * 4;
            const float4 r0 = *(const float4*)&rw[(size_t)(eg * 4 + 0) * DIN + colb];
            const float4 r1 = *(const float4*)&rw[(size_t)(eg * 4 + 1) * DIN + colb];
            const float4 r2 = *(const float4*)&rw[(size_t)(eg * 4 + 2) * DIN + colb];
            const float4 r3 = *(const float4*)&rw[(size_t)(eg * 4 + 3) * DIN + colb];
            #pragma unroll
            for (int t2 = 0; t2 < 2; ++t2) {
                const int t = ts * 2 + t2;
                const float4 xv = *(const float4*)&xsl[t][(j * 16 + cc) * 4];
                part[t2][0] += xv.x * r0.x + xv.y * r0.y + xv.z * r0.z + xv.w * r0.w;
                part[t2][1] += xv.x * r1.x + xv.y * r1.y + xv.z * r1.z + xv.w * r1.w;
                part[t2][2] += xv.x * r2.x + xv.y * r2.y + xv.z * r2.z + xv.w * r2.w;
                part[t2][3] += xv.x * r3.x + xv.y * r3.y + xv.z * r3.z + xv.w * r3.w;
            }
        }
        __syncthreads();
    }
    #pragma unroll
    for (int t2 = 0; t2 < 2; ++t2)
        #pragma unroll
        for (int e = 0; e < 4; ++e)
            red[ts * 2 + t2][eg * 4 + e][cc] = part[t2][e];
    __syncthreads();
    if (tid < 128) {
        const int t = tid >> 4, e = tid & 15;
        float s = 0.f;
        #pragma unroll
        for (int c = 0; c < 16; ++c) s += red[t][e][c];
        Corr[(size_t)(t0 + t) * NEXP + e] = s;
    }
}

// ---------- kernel 3: Z = Xhi @ W1^T  (M=8192, N=96, K=4096), split-K=8 ----------
// LDS chunk-swizzle: (row, chunk c) lives at chunk slot c ^ (row & 7).
__global__ void __launch_bounds__(256) gemm_prep_kernel(
        const unsigned short* __restrict__ Xcat,
        const unsigned short* __restrict__ W1, float* __restrict__ Z) {
    __shared__ __align__(16) unsigned short Xs[128 * 64];
    __shared__ __align__(16) unsigned short Ws[96 * 64];
    const int tid = threadIdx.x;
    const int wave = tid >> 6, lane = tid & 63;
    const int quad = lane >> 4, l16 = lane & 15;
    const int bm0 = blockIdx.x * 128;
    const int ks0 = blockIdx.y * 512;
    const int srow = tid >> 3;
    const int scol = ((tid & 7) ^ (srow & 7)) * 8;   // XOR-swizzled source chunk
    const int wm = wave * 32;
    f32x4 acc[2][6] = {};
    for (int kt = 0; kt < 8; ++kt) {
        const int k0 = ks0 + kt * 64;
        #pragma unroll
        for (int i = 0; i < 4; ++i)
            async_cp16(Xcat + (size_t)(bm0 + i * 32 + srow) * KCAT + k0 + scol,
                       (char*)Xs + i * 4096 + wave * 1024);
        #pragma unroll
        for (int i = 0; i < 3; ++i)
            async_cp16(W1 + (size_t)(i * 32 + srow) * DIN + k0 + scol,
                       (char*)Ws + i * 4096 + wave * 1024);
        __syncthreads();
        #pragma unroll
        for (int kk = 0; kk < 2; ++kk) {
            short8 am[2], bn[6];
            #pragma unroll
            for (int i = 0; i < 2; ++i)
                am[i] = *(const short8*)&Xs[(wm + i * 16 + l16) * 64 +
                                            (((kk * 4 + quad) ^ (l16 & 7)) << 3)];
            #pragma unroll
            for (int j = 0; j < 6; ++j)
                bn[j] = *(const short8*)&Ws[(j * 16 + l16) * 64 +
                                            (((kk * 4 + quad) ^ (l16 & 7)) << 3)];
            #pragma unroll
            for (int i = 0; i < 2; ++i)
                #pragma unroll
                for (int j = 0; j < 6; ++j)
                    acc[i][j] = __builtin_amdgcn_mfma_f32_16x16x32_bf16(
                        am[i], bn[j], acc[i][j], 0, 0, 0);
        }
        __syncthreads();
    }
    #pragma unroll
    for (int i = 0; i < 2; ++i) {
        const int row0 = bm0 + wm + i * 16 + quad * 4;
        #pragma unroll
        for (int j = 0; j < 6; ++j) {
            const int col = j * 16 + l16;
            #pragma unroll
            for (int r = 0; r < 4; ++r)
                atomicAdd(&Z[(size_t)(row0 + r) * 96 + col], acc[i][j][r]);
        }
    }
}

// ---------- kernel 4: softmax + top2 + build H16 ----------
__global__ void __launch_bounds__(256) finalize_kernel(
        const float* __restrict__ Z, const float* __restrict__ Corr,
        unsigned short* __restrict__ Xcat) {
    __shared__ __align__(16) unsigned short hb[4][1024];
    const int tid = threadIdx.x, wv = tid >> 6, lane = tid & 63;
    const int t = blockIdx.x * 4 + wv;
    const float h = Z[(size_t)t * 96 + lane];
    float l[16];
    #pragma unroll
    for (int e = 0; e < 16; ++e)
        l[e] = Z[(size_t)t * 96 + 64 + e] + Z[(size_t)t * 96 + 80 + e]
             + Corr[(size_t)t * NEXP + e];
    int i1 = 0; float b1v = l[0];
    #pragma unroll
    for (int e = 1; e < 16; ++e) if (l[e] > b1v) { b1v = l[e]; i1 = e; }
    int i2 = -1; float b2v = -1e30f;
    #pragma unroll
    for (int e = 0; e < 16; ++e) if (e != i1 && l[e] > b2v) { b2v = l[e]; i2 = e; }
    float S = 0.f;
    #pragma unroll
    for (int e = 0; e < 16; ++e) S += expf(l[e] - b1v);
    const float t1 = 1.0f / S;                 // p[i1]
    const float t2 = expf(b2v - b1v) / S;      // p[i2]
    const float d = t1 + t2 + 1e-6f;
    const float c1 = 0.5f * t1 / d;            // fold SCALING=0.5
    const float c2 = 0.5f * t2 / d;
    #pragma unroll
    for (int e = 0; e < 16; ++e) {
        const float v = (e == i1) ? c1 * h : (e == i2) ? c2 * h : 0.0f;
        hb[wv][e * 64 + lane] = f2bf(v);
    }
    __syncthreads();
    uint4* dst = (uint4*)(Xcat + (size_t)t * KCAT + DIN);
    const uint4* src = (const uint4*)hb[wv];
    dst[lane * 2] = src[lane * 2];
    dst[lane * 2 + 1] = src[lane * 2 + 1];
}

// ---------- kernel 5: out = Xcat @ Wcat^T + bias  (M=8192,N=4096,K=5120) ----------
// LDS chunk-swizzle: (row, chunk c) lives at chunk slot c ^ (row & 7).
__global__ void __launch_bounds__(256) gemm_main_kernel(
        const unsigned short* __restrict__ Xcat,
        const unsigned short* __restrict__ Wcat,
        const float* __restrict__ bias, float* __restrict__ out) {
    __shared__ __align__(16) unsigned short Xs[128 * 64];
    __shared__ __align__(16) unsigned short Ws[128 * 64];
    const int tid = threadIdx.x;
    const int wave = tid >> 6, lane = tid & 63;
    const int quad = lane >> 4, l16 = lane & 15;
    const int bn0 = blockIdx.x * 128;
    const int bm0 = blockIdx.y * 128;
    const int srow = tid >> 3;
    const int scol = ((tid & 7) ^ (srow & 7)) * 8;   // XOR-swizzled source chunk
    const unsigned short* gx = Xcat + (size_t)(bm0 + srow) * KCAT + scol;
    const unsigned short* gw = Wcat + (size_t)(bn0 + srow) * KCAT + scol;
    const int wm0 = (wave & 1) * 64;
    const int wn0 = (wave >> 1) * 64;
    f32x4 acc[4][4] = {};
    for (int kt = 0; kt < KCAT / 64; ++kt) {
        const int k0 = kt * 64;
        #pragma unroll
        for (int i = 0; i < 4; ++i) {
            async_cp16(gx + (size_t)(i * 32) * KCAT + k0, (char*)Xs + i * 4096 + wave * 1024);
            async_cp16(gw + (size_t)(i * 32) * KCAT + k0, (char*)Ws + i * 4096 + wave * 1024);
        }
        __syncthreads();
        #pragma unroll
        for (int kk = 0; kk < 2; ++kk) {
            short8 am[4], bn[4];
            #pragma unroll
            for (int i = 0; i < 4; ++i)
                am[i] = *(const short8*)&Xs[(wm0 + i * 16 + l16) * 64 +
                                            (((kk * 4 + quad) ^ (l16 & 7)) << 3)];
            #pragma unroll
            for (int j = 0; j < 4; ++j)
                bn[j] = *(const short8*)&Ws[(wn0 + j * 16 + l16) * 64 +
                                            (((kk * 4 + quad) ^ (l16 & 7)) << 3)];
            #pragma unroll
            for (int i = 0; i < 4; ++i)
                #pragma unroll
                for (int j = 0; j < 4; ++j)
                    acc[i][j] = __builtin_amdgcn_mfma_f32_16x16x32_bf16(
                        am[i], bn[j], acc[i][j], 0, 0, 0);
        }
        __syncthreads();
    }
    #pragma unroll
    for (int j = 0; j < 4; ++j) {
        const int col = bn0 + wn0 + j * 16 + l16;
        const float bj = bias[col];
        #pragma unroll
        for (int i = 0; i < 4; ++i) {
            const int row0 = bm0 + wm0 + i * 16 + quad * 4;
            #pragma unroll
            for (int r = 0; r < 4; ++r)
                out[(size_t)(row0 + r) * DOUT + col] = acc[i][j][r] + bj;
        }
    }
}

// ---------- host ----------
extern "C" void kernel_launch(void* const* d_in, const int* in_sizes, int n_in,
                              void* d_out, int out_size, void* d_ws, size_t ws_size,
                              hipStream_t stream) {
    const float* x  = (const float*)d_in[0];
    const float* bw = (const float*)d_in[1];
    const float* bb = (const float*)d_in[2];
    const float* Am = (const float*)d_in[3];
    const float* Bm = (const float*)d_in[4];
    const float* rw = (const float*)d_in[5];
    float* out = (float*)d_out;
    char* ws = (char*)d_ws;
    unsigned short* Xcat = (unsigned short*)(ws);                 // 8192*5120*2 = 83,886,080
    unsigned short* Wcat = (unsigned short*)(ws + 83886080);      // 4096*5120*2 = 41,943,040
    unsigned short* W1   = (unsigned short*)(ws + 125829120);     // 96*4096*2   =    786,432
    float* Z    = (float*)(ws + 126615552);                       // 8192*96*4   =  3,145,728
    float* Corr = (float*)(ws + 129761280);                       // 8192*16*4   =    524,288

    hipLaunchKernelGGL(prep_w_kernel,   dim3(4096),   dim3(256), 0, stream, bw, Bm, Am, rw, Wcat, W1);
    hipLaunchKernelGGL(prep_x_kernel,   dim3(1024),   dim3(256), 0, stream, x, rw, Xcat, Corr, Z);
    hipLaunchKernelGGL(gemm_prep_kernel,dim3(64, 8),  dim3(256), 0, stream, Xcat, W1, Z);
    hipLaunchKernelGGL(finalize_kernel, dim3(2048),   dim3(256), 0, stream, Z, Corr, Xcat);
    hipLaunchKernelGGL(gemm_main_kernel,dim3(32, 64), dim3(256), 0, stream, Xcat, Wcat, bb, out);
}